// Round 2
// baseline (15899.272 us; speedup 1.0000x reference)
//
#include <hip/hip_runtime.h>

#define N_PTS 65536
#define K_CB  8192
#define D_DIM 64

constexpr int BN  = 128;   // rows per block
constexpr int BK  = 128;   // codebook rows per LDS chunk
constexpr int LDT = 140;   // padded/swizzled LDS row stride (floats)

// swizzle: col -> col + 4*(col/32). Keeps 8-float chunks contiguous &
// 16B-aligned, spreads the 16 tx-lane b128 reads to 2-way bank overlap (free).
__device__ __forceinline__ int swz(int c) { return c + 4 * (c >> 5); }

// Row-wise sum of squares replicating numpy fp32 pairwise order (n=64 path):
//   w[i] = fl(x_i*x_i);  r[j] = w[j]; for i=8,16,...,56: r[j] += w[i+j];
//   res = ((r0+r1)+(r2+r3)) + ((r4+r5)+(r6+r7))
// One wave per 64 rows; lane d holds w[d]; lanes 0..7 build r_j via shfl.
__global__ void vq_sumsq(const float* __restrict__ src, float* __restrict__ dst,
                         float* __restrict__ acc, int zero_acc) {
#pragma clang fp contract(off)
    int gtid = blockIdx.x * blockDim.x + threadIdx.x;
    if (zero_acc && gtid == 0) *acc = 0.f;
    int wid  = gtid >> 6;
    int lane = threadIdx.x & 63;
    int row0 = wid * 64;
    for (int r = 0; r < 64; ++r) {
        int row = row0 + r;
        float v = src[(size_t)row * D_DIM + lane];
        float w = v * v;                       // rounded square BEFORE any add
        float ra = w;                          // lanes 0..7: numpy r[j]
#pragma unroll
        for (int i = 1; i < 8; ++i)
            ra = ra + __shfl(w, lane + 8 * i, 64);   // sequential, i ascending
        float r0 = __shfl(ra, 0, 64), r1 = __shfl(ra, 1, 64),
              r2 = __shfl(ra, 2, 64), r3 = __shfl(ra, 3, 64),
              r4 = __shfl(ra, 4, 64), r5 = __shfl(ra, 5, 64),
              r6 = __shfl(ra, 6, 64), r7 = __shfl(ra, 7, 64);
        if (lane == 0)
            dst[row] = ((r0 + r1) + (r2 + r3)) + ((r4 + r5) + (r6 + r7));
    }
}

__global__ __launch_bounds__(256, 3) void vq_argmin(
        const float* __restrict__ z, const float* __restrict__ cb,
        const float* __restrict__ e2, const float* __restrict__ x2,
        float* __restrict__ oidx) {
    __shared__ float cT[64 * LDT];
    const int tid = threadIdx.x;
    const int tx = tid & 15, ty = tid >> 4;   // tx: 16 col-groups x8, ty: 16 row-groups x8
    const int n0 = blockIdx.x * BN;
    const int cbase = swz(8 * tx);

    // per-row |z|^2 (numpy-pairwise, precomputed) — the reference keeps this
    // term, and its fp32 quantization at ~64-scale DEFINES the tie structure.
    float x2v[8];
#pragma unroll
    for (int i = 0; i < 8; ++i) x2v[i] = x2[n0 + 8 * ty + i];

    float minv[8];
    int   mini[8];
#pragma unroll
    for (int i = 0; i < 8; ++i) { minv[i] = 3.4e38f; mini[i] = 0; }

    for (int kc = 0; kc < K_CB / BK; ++kc) {
        __syncthreads();   // prev-chunk reads done before overwrite
        {
            // stage codebook chunk transposed: cT[d][col] (swizzled)
            const float4* c4 = (const float4*)(cb + (size_t)kc * BK * D_DIM);
#pragma unroll
            for (int i = 0; i < 8; ++i) {
                int lin = tid + 256 * i;
                int row = lin >> 4, d4 = lin & 15;
                float4 v = c4[row * 16 + d4];
                float* p = &cT[(4 * d4) * LDT + swz(row)];
                p[0 * LDT] = v.x; p[1 * LDT] = v.y;
                p[2 * LDT] = v.z; p[3 * LDT] = v.w;
            }
        }
        __syncthreads();

        float acc[8][8];
#pragma unroll
        for (int i = 0; i < 8; ++i)
#pragma unroll
            for (int j = 0; j < 8; ++j) acc[i][j] = 0.f;

#pragma unroll
        for (int dc = 0; dc < 16; ++dc) {
            // z chunk: 8 rows x 4 d, straight from global (L1 broadcast across
            // the 16 same-ty lanes), keeps LDS bandwidth for the codebook only.
            float zf[8][4];
#pragma unroll
            for (int i = 0; i < 8; ++i) {
                float4 v = *(const float4*)(z + (size_t)(n0 + 8 * ty + i) * D_DIM + dc * 4);
                zf[i][0] = v.x; zf[i][1] = v.y; zf[i][2] = v.z; zf[i][3] = v.w;
            }
#pragma unroll
            for (int dd = 0; dd < 4; ++dd) {
                const float* cp = &cT[(dc * 4 + dd) * LDT + cbase];
                float4 ca = *(const float4*)cp;
                float4 cb2 = *(const float4*)(cp + 4);
                float cf[8] = {ca.x, ca.y, ca.z, ca.w, cb2.x, cb2.y, cb2.z, cb2.w};
#pragma unroll
                for (int i = 0; i < 8; ++i)
#pragma unroll
                    for (int j = 0; j < 8; ++j)
                        acc[i][j] = fmaf(zf[i][dd], cf[j], acc[i][j]);
            }
        }

        // Emulate reference rounding: d2 = fl( fl(x2 - 2g) + e2 ).
        // fmaf(-2,g,x2) == fl(x2 - fl(2g)) exactly (2g is an exact scaling).
        // Near-min candidates within ulp(~64)=7.6e-6 become EXACT ties, broken
        // by lowest index everywhere — matching np.argmin first-occurrence.
        int k0 = kc * BK + 8 * tx;
        float4 ea = *(const float4*)(e2 + k0);
        float4 eb = *(const float4*)(e2 + k0 + 4);
        float ev[8] = {ea.x, ea.y, ea.z, ea.w, eb.x, eb.y, eb.z, eb.w};
#pragma unroll
        for (int j = 0; j < 8; ++j) {
            int k = k0 + j;
#pragma unroll
            for (int i = 0; i < 8; ++i) {
                float s1 = fmaf(-2.f, acc[i][j], x2v[i]);
                float s  = s1 + ev[j];
                if (s < minv[i]) { minv[i] = s; mini[i] = k; }   // strict <: first min wins
            }
        }
    }

    // reduce over the 16 tx lanes (same ty => same rows); lower index on ties
#pragma unroll
    for (int m = 1; m < 16; m <<= 1) {
#pragma unroll
        for (int i = 0; i < 8; ++i) {
            float ov = __shfl_xor(minv[i], m, 64);
            int   oi = __shfl_xor(mini[i], m, 64);
            if (ov < minv[i] || (ov == minv[i] && oi < mini[i])) {
                minv[i] = ov; mini[i] = oi;
            }
        }
    }
    if (tx == 0) {
#pragma unroll
        for (int i = 0; i < 8; ++i) {
            int n = n0 + 8 * ty + i;
            oidx[n] = (float)mini[i];   // out buffer read back as f32; exact for k<2^24
        }
    }
}

__global__ void vq_gather(const float* __restrict__ z, const float* __restrict__ cb,
                          const float* __restrict__ idxf, float* __restrict__ out,
                          float* __restrict__ acc) {
    int tid  = threadIdx.x;
    int lane = tid & 63;
    int n    = blockIdx.x * 4 + (tid >> 6);   // one wave per row
    int best = (int)idxf[n];
    float ze = z[(size_t)n * D_DIM + lane];
    float zq = cb[(size_t)best * D_DIM + lane];
    out[(size_t)n * D_DIM + lane] = ze + (zq - ze);   // straight-through, reference rounding
    float d = ze - zq;
    d = d * d;
#pragma unroll
    for (int m = 32; m > 0; m >>= 1) d += __shfl_xor(d, m, 64);
    __shared__ float part[4];
    if (lane == 0) part[tid >> 6] = d;
    __syncthreads();
    if (tid == 0) atomicAdd(acc, part[0] + part[1] + part[2] + part[3]);
}

__global__ void vq_final(const float* __restrict__ acc, float* __restrict__ out_loss) {
    // vq_loss = codebook_loss + 0.25*commitment_loss = 1.25 * mse (identical values)
    *out_loss = 1.25f * (*acc) / (float)(N_PTS * D_DIM);
}

extern "C" void kernel_launch(void* const* d_in, const int* in_sizes, int n_in,
                              void* d_out, int out_size, void* d_ws, size_t ws_size,
                              hipStream_t stream) {
    const float* z  = (const float*)d_in[0];
    const float* cb = (const float*)d_in[1];
    float* out      = (float*)d_out;
    float* zq_out   = out;                              // [N*D]
    float* loss_out = out + (size_t)N_PTS * D_DIM;      // [1]
    float* idx_out  = loss_out + 1;                     // [N], written as float

    float* wsf = (float*)d_ws;
    float* acc = wsf;            // 1 float (16-float slot for alignment)
    float* e2  = wsf + 16;       // K floats
    float* x2  = wsf + 16 + K_CB;// N floats

    vq_sumsq <<<K_CB  / 256, 256, 0, stream>>>(cb, e2, acc, 1);
    vq_sumsq <<<N_PTS / 256, 256, 0, stream>>>(z,  x2, acc, 0);
    vq_argmin<<<N_PTS / BN, 256, 0, stream>>>(z, cb, e2, x2, idx_out);
    vq_gather<<<N_PTS / 4, 256, 0, stream>>>(z, cb, idx_out, zq_out, acc);
    vq_final <<<1, 1, 0, stream>>>(acc, loss_out);
}

// Round 3
// 1218.207 us; speedup vs baseline: 13.0514x; 13.0514x over previous
//
#include <hip/hip_runtime.h>

#define N_PTS 65536
#define K_CB  8192
#define D_DIM 64

constexpr int BN = 128;   // z rows per block
constexpr int BK = 128;   // codebook rows per LDS chunk

// Row-wise sum of squares replicating numpy fp32 pairwise order (n=64 path).
__global__ void vq_sumsq(const float* __restrict__ src, float* __restrict__ dst,
                         float* __restrict__ acc, int zero_acc) {
#pragma clang fp contract(off)
    int gtid = blockIdx.x * blockDim.x + threadIdx.x;
    if (zero_acc && gtid == 0) *acc = 0.f;
    int wid  = gtid >> 6;
    int lane = threadIdx.x & 63;
    int row0 = wid * 64;
    for (int r = 0; r < 64; ++r) {
        int row = row0 + r;
        float v = src[(size_t)row * D_DIM + lane];
        float w = v * v;
        float ra = w;
#pragma unroll
        for (int i = 1; i < 8; ++i)
            ra = ra + __shfl(w, lane + 8 * i, 64);
        float r0 = __shfl(ra, 0, 64), r1 = __shfl(ra, 1, 64),
              r2 = __shfl(ra, 2, 64), r3 = __shfl(ra, 3, 64),
              r4 = __shfl(ra, 4, 64), r5 = __shfl(ra, 5, 64),
              r6 = __shfl(ra, 6, 64), r7 = __shfl(ra, 7, 64);
        if (lane == 0)
            dst[row] = ((r0 + r1) + (r2 + r3)) + ((r4 + r5) + (r6 + r7));
    }
}

__global__ __launch_bounds__(256, 2) void vq_argmin(
        const float* __restrict__ z, const float* __restrict__ cb,
        const float* __restrict__ e2, const float* __restrict__ x2,
        float* __restrict__ oidx) {
    // cT[r][col]: codebook chunk transposed (r = dim 0..63, col = chunk row 0..127)
    //   element at r*128 + (col ^ 4*((col>>5)&3) ^ 8*((r>>2)&3))  — 32 KB, no pad
    // zT[row][d]: z tile, element at row*64 + ((4*(d>>2)*... rotation) — 32 KB
    __shared__ float cT[64 * 128];
    __shared__ float zT[128 * 64];
    const int tid = threadIdx.x;
    const int tx = tid & 15, ty = tid >> 4;
    const int n0 = blockIdx.x * BN;

    // ---- stage z tile ONCE per block (this was 28 GB of L2-miss traffic before) ----
    {
        const float4* z4 = (const float4*)(z + (size_t)n0 * D_DIM);
#pragma unroll
        for (int i = 0; i < 8; ++i) {
            int lin = tid + 256 * i;
            int row = lin >> 4, d4 = lin & 15;      // z4[row*16+d4] == z4[lin]
            float4 v = z4[lin];
            int col = (4 * d4 + 8 * ((row >> 3) & 3)) & 63;   // bank rotation
            *(float4*)&zT[row * 64 + col] = v;
        }
    }

    float x2v[8];
#pragma unroll
    for (int i = 0; i < 8; ++i) x2v[i] = x2[n0 + 8 * ty + i];

    float minv[8];
    int   mini[8];
#pragma unroll
    for (int i = 0; i < 8; ++i) { minv[i] = 3.4e38f; mini[i] = 0; }

    const int zs = 8 * (ty & 3);          // z read rotation (row>>3 == ty for our rows)
    const int c0 = 8 * tx;
    const int o0base = c0 ^ (4 * ((c0 >> 5) & 3));
    const int o1base = (c0 + 4) ^ (4 * (((c0 + 4) >> 5) & 3));

    for (int kc = 0; kc < K_CB / BK; ++kc) {
        __syncthreads();   // prev-chunk cT reads done before overwrite
        {
            const float4* c4 = (const float4*)(cb + (size_t)kc * BK * D_DIM);
#pragma unroll
            for (int i = 0; i < 8; ++i) {
                int lin = tid + 256 * i;
                int colrow = lin >> 4, d4 = lin & 15;   // c4[lin] = chunk row colrow, dims 4d4..+3
                float4 v = c4[lin];
                int cs = (colrow ^ (4 * ((colrow >> 5) & 3))) ^ (8 * (d4 & 3));
                cT[(4 * d4 + 0) * 128 + cs] = v.x;
                cT[(4 * d4 + 1) * 128 + cs] = v.y;
                cT[(4 * d4 + 2) * 128 + cs] = v.z;
                cT[(4 * d4 + 3) * 128 + cs] = v.w;
            }
        }
        __syncthreads();

        float acc[8][8];
#pragma unroll
        for (int i = 0; i < 8; ++i)
#pragma unroll
            for (int j = 0; j < 8; ++j) acc[i][j] = 0.f;

#pragma unroll
        for (int dc = 0; dc < 16; ++dc) {
            float zf[8][4];
            int zcol = (4 * dc + zs) & 63;
#pragma unroll
            for (int i = 0; i < 8; ++i) {
                float4 v = *(const float4*)&zT[(8 * ty + i) * 64 + zcol];
                zf[i][0] = v.x; zf[i][1] = v.y; zf[i][2] = v.z; zf[i][3] = v.w;
            }
            int gg = 8 * (dc & 3);
#pragma unroll
            for (int dd = 0; dd < 4; ++dd) {
                const float* crow = &cT[(4 * dc + dd) * 128];
                float4 ca  = *(const float4*)&crow[o0base ^ gg];
                float4 cb2 = *(const float4*)&crow[o1base ^ gg];
                float cf[8] = {ca.x, ca.y, ca.z, ca.w, cb2.x, cb2.y, cb2.z, cb2.w};
#pragma unroll
                for (int i = 0; i < 8; ++i)
#pragma unroll
                    for (int j = 0; j < 8; ++j)
                        acc[i][j] = fmaf(zf[i][dd], cf[j], acc[i][j]);
            }
        }

        // Reference rounding: d2 = fl( fl(x2 - 2g) + e2 ); exact ties -> lowest index.
        int k0 = kc * BK + 8 * tx;
        float4 ea = *(const float4*)(e2 + k0);
        float4 eb = *(const float4*)(e2 + k0 + 4);
        float ev[8] = {ea.x, ea.y, ea.z, ea.w, eb.x, eb.y, eb.z, eb.w};
#pragma unroll
        for (int j = 0; j < 8; ++j) {
            int k = k0 + j;
#pragma unroll
            for (int i = 0; i < 8; ++i) {
                float s1 = fmaf(-2.f, acc[i][j], x2v[i]);
                float s  = s1 + ev[j];
                if (s < minv[i]) { minv[i] = s; mini[i] = k; }
            }
        }
    }

    // reduce over the 16 tx lanes; lower index on ties
#pragma unroll
    for (int m = 1; m < 16; m <<= 1) {
#pragma unroll
        for (int i = 0; i < 8; ++i) {
            float ov = __shfl_xor(minv[i], m, 64);
            int   oi = __shfl_xor(mini[i], m, 64);
            if (ov < minv[i] || (ov == minv[i] && oi < mini[i])) {
                minv[i] = ov; mini[i] = oi;
            }
        }
    }
    if (tx == 0) {
#pragma unroll
        for (int i = 0; i < 8; ++i) {
            int n = n0 + 8 * ty + i;
            oidx[n] = (float)mini[i];
        }
    }
}

__global__ void vq_gather(const float* __restrict__ z, const float* __restrict__ cb,
                          const float* __restrict__ idxf, float* __restrict__ out,
                          float* __restrict__ acc) {
    int tid  = threadIdx.x;
    int lane = tid & 63;
    int n    = blockIdx.x * 4 + (tid >> 6);
    int best = (int)idxf[n];
    float ze = z[(size_t)n * D_DIM + lane];
    float zq = cb[(size_t)best * D_DIM + lane];
    out[(size_t)n * D_DIM + lane] = ze + (zq - ze);
    float d = ze - zq;
    d = d * d;
#pragma unroll
    for (int m = 32; m > 0; m >>= 1) d += __shfl_xor(d, m, 64);
    __shared__ float part[4];
    if (lane == 0) part[tid >> 6] = d;
    __syncthreads();
    if (tid == 0) atomicAdd(acc, part[0] + part[1] + part[2] + part[3]);
}

__global__ void vq_final(const float* __restrict__ acc, float* __restrict__ out_loss) {
    *out_loss = 1.25f * (*acc) / (float)(N_PTS * D_DIM);
}

extern "C" void kernel_launch(void* const* d_in, const int* in_sizes, int n_in,
                              void* d_out, int out_size, void* d_ws, size_t ws_size,
                              hipStream_t stream) {
    const float* z  = (const float*)d_in[0];
    const float* cb = (const float*)d_in[1];
    float* out      = (float*)d_out;
    float* zq_out   = out;
    float* loss_out = out + (size_t)N_PTS * D_DIM;
    float* idx_out  = loss_out + 1;

    float* wsf = (float*)d_ws;
    float* acc = wsf;
    float* e2  = wsf + 16;
    float* x2  = wsf + 16 + K_CB;

    vq_sumsq <<<K_CB  / 256, 256, 0, stream>>>(cb, e2, acc, 1);
    vq_sumsq <<<N_PTS / 256, 256, 0, stream>>>(z,  x2, acc, 0);
    vq_argmin<<<N_PTS / BN, 256, 0, stream>>>(z, cb, e2, x2, idx_out);
    vq_gather<<<N_PTS / 4, 256, 0, stream>>>(z, cb, idx_out, zq_out, acc);
    vq_final <<<1, 1, 0, stream>>>(acc, loss_out);
}

// Round 4
// 615.258 us; speedup vs baseline: 25.8416x; 1.9800x over previous
//
#include <hip/hip_runtime.h>

#define N_PTS 65536
#define K_CB  8192
#define D_DIM 64
#define CAP   24

typedef float f32x4 __attribute__((ext_vector_type(4)));
typedef short s16x8 __attribute__((ext_vector_type(8)));

__device__ __forceinline__ unsigned short f2bf(float f) {   // RNE fp32->bf16
    unsigned int u = __float_as_uint(f);
    return (unsigned short)((u + 0x7fffu + ((u >> 16) & 1u)) >> 16);
}

// ---- prep: numpy-pairwise row sum-of-squares (bit-exact, as round 3) + bf16 copy ----
__global__ __launch_bounds__(256) void vq_prep_cb(
        const float* __restrict__ src, float* __restrict__ e2,
        unsigned short* __restrict__ dst16, int* __restrict__ e2max_bits) {
#pragma clang fp contract(off)
    int gtid = blockIdx.x * 256 + threadIdx.x;
    int wid = gtid >> 6, lane = threadIdx.x & 63;
    float lmax = 0.f;
    for (int r = 0; r < 16; ++r) {
        int row = wid * 16 + r;
        float v = src[(size_t)row * D_DIM + lane];
        dst16[(size_t)row * D_DIM + lane] = f2bf(v);
        float w = v * v;
        float ra = w;
#pragma unroll
        for (int i = 1; i < 8; ++i) ra = ra + __shfl(w, lane + 8 * i, 64);
        float r0 = __shfl(ra, 0, 64), r1 = __shfl(ra, 1, 64),
              r2 = __shfl(ra, 2, 64), r3 = __shfl(ra, 3, 64),
              r4 = __shfl(ra, 4, 64), r5 = __shfl(ra, 5, 64),
              r6 = __shfl(ra, 6, 64), r7 = __shfl(ra, 7, 64);
        if (lane == 0) {
            float s = ((r0 + r1) + (r2 + r3)) + ((r4 + r5) + (r6 + r7));
            e2[row] = s;
            lmax = fmaxf(lmax, s);
        }
    }
    if (lane == 0) atomicMax(e2max_bits, __float_as_int(lmax));  // positive floats: int-monotone
}

__global__ __launch_bounds__(256) void vq_prep_z(
        const float* __restrict__ src, float* __restrict__ x2,
        unsigned short* __restrict__ dst16) {
#pragma clang fp contract(off)
    int gtid = blockIdx.x * 256 + threadIdx.x;
    int wid = gtid >> 6, lane = threadIdx.x & 63;
    for (int r = 0; r < 16; ++r) {
        int row = wid * 16 + r;
        float v = src[(size_t)row * D_DIM + lane];
        dst16[(size_t)row * D_DIM + lane] = f2bf(v);
        float w = v * v;
        float ra = w;
#pragma unroll
        for (int i = 1; i < 8; ++i) ra = ra + __shfl(w, lane + 8 * i, 64);
        float r0 = __shfl(ra, 0, 64), r1 = __shfl(ra, 1, 64),
              r2 = __shfl(ra, 2, 64), r3 = __shfl(ra, 3, 64),
              r4 = __shfl(ra, 4, 64), r5 = __shfl(ra, 5, 64),
              r6 = __shfl(ra, 6, 64), r7 = __shfl(ra, 7, 64);
        if (lane == 0)
            x2[row] = ((r0 + r1) + (r2 + r3)) + ((r4 + r5) + (r6 + r7));
    }
}

// ---- coarse MFMA kernel: 128 rows/block, two sweeps over K ----
// LDS layout (bf16, swizzled): row*64 + ((unit ^ (row&7))*8), unit = d>>3.
// A/B frag (16x16x32 bf16): lane l supplies op[m = l&15][k = (l>>4)*8 + j].
// C/D: col = lane&15, row = (lane>>4)*4 + reg  [measured m89/m91].
__global__ __launch_bounds__(256, 3) void vq_coarse(
        const unsigned short* __restrict__ z16,
        const unsigned short* __restrict__ c16,
        const float* __restrict__ e2, const float* __restrict__ x2,
        const int* __restrict__ e2max_bits,
        int* __restrict__ cand, int* __restrict__ cnt) {
    __shared__ __align__(16) unsigned short zb[128 * 64];   // 16 KB
    __shared__ __align__(16) unsigned short cbb[256 * 64];  // 32 KB
    __shared__ float e2s[256];
    __shared__ float mtT[128];
    __shared__ int   cntS[128];

    const int tid = threadIdx.x;
    const int w = tid >> 6, l = tid & 63, tx = l & 15, q = l >> 4;
    const int n0 = blockIdx.x * 128;

    {   // stage z tile once (bf16): 128 rows x 8 units
        const uint4* g = (const uint4*)(z16 + (size_t)n0 * D_DIM);
#pragma unroll
        for (int i = 0; i < 4; ++i) {
            int lin = tid + 256 * i;
            int row = lin >> 3, u = lin & 7;
            uint4 v = g[lin];
            *(uint4*)&zb[row * 64 + ((u ^ (row & 7)) * 8)] = v;
        }
    }
    __syncthreads();

    // A-frags register-resident for the WHOLE kernel (zero A LDS traffic in loop)
    s16x8 afr[2][2];
#pragma unroll
    for (int rt = 0; rt < 2; ++rt)
#pragma unroll
        for (int ks = 0; ks < 2; ++ks) {
            int row = w * 32 + rt * 16 + tx;
            afr[rt][ks] = *(const s16x8*)&zb[row * 64 + (((ks * 4 + q) ^ (tx & 7)) * 8)];
        }

    float minv[8];
#pragma unroll
    for (int i = 0; i < 8; ++i) minv[i] = 3.4e38f;

    // ---------------- sweep 1: coarse per-row min ----------------
    for (int kc = 0; kc < K_CB / 256; ++kc) {
        __syncthreads();
        {
            const uint4* g = (const uint4*)(c16 + (size_t)kc * 256 * D_DIM);
#pragma unroll
            for (int i = 0; i < 8; ++i) {
                int lin = tid + 256 * i;
                int row = lin >> 3, u = lin & 7;
                uint4 v = g[lin];
                *(uint4*)&cbb[row * 64 + ((u ^ (row & 7)) * 8)] = v;
            }
            e2s[tid] = e2[kc * 256 + tid];
        }
        __syncthreads();
        for (int ct = 0; ct < 16; ++ct) {
            int crow = ct * 16 + tx;
            s16x8 b0 = *(const s16x8*)&cbb[crow * 64 + (((0 + q) ^ (tx & 7)) * 8)];
            s16x8 b1 = *(const s16x8*)&cbb[crow * 64 + (((4 + q) ^ (tx & 7)) * 8)];
            float e2v = e2s[crow];
#pragma unroll
            for (int rt = 0; rt < 2; ++rt) {
                f32x4 acc = {0.f, 0.f, 0.f, 0.f};
                acc = __builtin_amdgcn_mfma_f32_16x16x32_bf16(afr[rt][0], b0, acc, 0, 0, 0);
                acc = __builtin_amdgcn_mfma_f32_16x16x32_bf16(afr[rt][1], b1, acc, 0, 0, 0);
#pragma unroll
                for (int r = 0; r < 4; ++r) {
                    float t = fmaf(-2.f, acc[r], e2v);
                    minv[rt * 4 + r] = fminf(minv[rt * 4 + r], t);
                }
            }
        }
    }
#pragma unroll
    for (int m = 1; m < 16; m <<= 1)
#pragma unroll
        for (int i = 0; i < 8; ++i)
            minv[i] = fminf(minv[i], __shfl_xor(minv[i], m, 64));
    if (tx == 0) {
#pragma unroll
        for (int rt = 0; rt < 2; ++rt)
#pragma unroll
            for (int r = 0; r < 4; ++r)
                mtT[w * 32 + rt * 16 + q * 4 + r] = minv[rt * 4 + r];
    }
    __syncthreads();
    if (tid < 128) {
        // guaranteed bf16-error window: 2*B2 + slack, B2 <= 0.0165*sqrt(x2*e2max)
        float e2m = __int_as_float(*e2max_bits);
        mtT[tid] += 0.035f * sqrtf(x2[n0 + tid] * e2m) + 2e-4f;
        cntS[tid] = 0;
    }
    __syncthreads();

    f32x4 Tq[2];
#pragma unroll
    for (int rt = 0; rt < 2; ++rt)
        Tq[rt] = *(const f32x4*)&mtT[w * 32 + rt * 16 + q * 4];

    // ---------------- sweep 2: bitwise replay, collect candidates ----------------
    for (int kc = 0; kc < K_CB / 256; ++kc) {
        __syncthreads();
        {
            const uint4* g = (const uint4*)(c16 + (size_t)kc * 256 * D_DIM);
#pragma unroll
            for (int i = 0; i < 8; ++i) {
                int lin = tid + 256 * i;
                int row = lin >> 3, u = lin & 7;
                uint4 v = g[lin];
                *(uint4*)&cbb[row * 64 + ((u ^ (row & 7)) * 8)] = v;
            }
            e2s[tid] = e2[kc * 256 + tid];
        }
        __syncthreads();
        for (int ct = 0; ct < 16; ++ct) {
            int crow = ct * 16 + tx;
            s16x8 b0 = *(const s16x8*)&cbb[crow * 64 + (((0 + q) ^ (tx & 7)) * 8)];
            s16x8 b1 = *(const s16x8*)&cbb[crow * 64 + (((4 + q) ^ (tx & 7)) * 8)];
            float e2v = e2s[crow];
#pragma unroll
            for (int rt = 0; rt < 2; ++rt) {
                f32x4 acc = {0.f, 0.f, 0.f, 0.f};
                acc = __builtin_amdgcn_mfma_f32_16x16x32_bf16(afr[rt][0], b0, acc, 0, 0, 0);
                acc = __builtin_amdgcn_mfma_f32_16x16x32_bf16(afr[rt][1], b1, acc, 0, 0, 0);
#pragma unroll
                for (int r = 0; r < 4; ++r) {
                    float t = fmaf(-2.f, acc[r], e2v);   // bitwise == sweep 1
                    if (t <= Tq[rt][r]) {
                        int row = w * 32 + rt * 16 + q * 4 + r;
                        int slot = atomicAdd(&cntS[row], 1);
                        if (slot < CAP)
                            cand[(size_t)(n0 + row) * CAP + slot] = kc * 256 + crow;
                    }
                }
            }
        }
    }
    __syncthreads();
    if (tid < 128) cnt[n0 + tid] = cntS[tid];
}

// ---- exact fp32 rescore: bit-identical to round-3 pipeline ----
__device__ __forceinline__ float exact_score(const float* zr, const float* __restrict__ cb,
                                             const float* __restrict__ e2, float x2v, int k) {
    const float4* c4 = (const float4*)(cb + (size_t)k * D_DIM);
    float g = 0.f;
#pragma unroll
    for (int j = 0; j < 16; ++j) {            // sequential fmaf, d ascending (round-3 order)
        float4 v = c4[j];
        g = fmaf(zr[4 * j + 0], v.x, g);
        g = fmaf(zr[4 * j + 1], v.y, g);
        g = fmaf(zr[4 * j + 2], v.z, g);
        g = fmaf(zr[4 * j + 3], v.w, g);
    }
    return fmaf(-2.f, g, x2v) + e2[k];        // fl(fl(x2-2g)+e2)
}

__global__ __launch_bounds__(256) void vq_rescore(
        const float* __restrict__ z, const float* __restrict__ cb,
        const float* __restrict__ e2, const float* __restrict__ x2,
        const int* __restrict__ cand, const int* __restrict__ cnt,
        float* __restrict__ oidx) {
    int n = blockIdx.x * 256 + threadIdx.x;
    float zr[64];
    const float4* z4 = (const float4*)(z + (size_t)n * D_DIM);
#pragma unroll
    for (int i = 0; i < 16; ++i) {
        float4 v = z4[i];
        zr[4 * i] = v.x; zr[4 * i + 1] = v.y; zr[4 * i + 2] = v.z; zr[4 * i + 3] = v.w;
    }
    float x2v = x2[n];
    int c = cnt[n];
    float bs = 3.4e38f; int bk = 0x7fffffff;
    if (c <= CAP) {
        for (int i = 0; i < c; ++i) {
            int k = cand[(size_t)n * CAP + i];
            float s = exact_score(zr, cb, e2, x2v, k);
            if (s < bs || (s == bs && k < bk)) { bs = s; bk = k; }
        }
    } else {   // overflow fallback: guaranteed-correct full scan (≈never taken)
        for (int k = 0; k < K_CB; ++k) {
            float s = exact_score(zr, cb, e2, x2v, k);
            if (s < bs || (s == bs && k < bk)) { bs = s; bk = k; }
        }
    }
    oidx[n] = (float)bk;
}

__global__ void vq_gather(const float* __restrict__ z, const float* __restrict__ cb,
                          const float* __restrict__ idxf, float* __restrict__ out,
                          float* __restrict__ acc) {
    int tid  = threadIdx.x;
    int lane = tid & 63;
    int n    = blockIdx.x * 4 + (tid >> 6);
    int best = (int)idxf[n];
    float ze = z[(size_t)n * D_DIM + lane];
    float zq = cb[(size_t)best * D_DIM + lane];
    out[(size_t)n * D_DIM + lane] = ze + (zq - ze);
    float d = ze - zq;
    d = d * d;
#pragma unroll
    for (int m = 32; m > 0; m >>= 1) d += __shfl_xor(d, m, 64);
    __shared__ float part[4];
    if (lane == 0) part[tid >> 6] = d;
    __syncthreads();
    if (tid == 0) atomicAdd(acc, part[0] + part[1] + part[2] + part[3]);
}

__global__ void vq_final(const float* __restrict__ acc, float* __restrict__ out_loss) {
    *out_loss = 1.25f * (*acc) / (float)(N_PTS * D_DIM);
}

extern "C" void kernel_launch(void* const* d_in, const int* in_sizes, int n_in,
                              void* d_out, int out_size, void* d_ws, size_t ws_size,
                              hipStream_t stream) {
    const float* z  = (const float*)d_in[0];
    const float* cb = (const float*)d_in[1];
    float* out      = (float*)d_out;
    float* zq_out   = out;                              // [N*D], written LAST by gather
    float* loss_out = out + (size_t)N_PTS * D_DIM;
    float* idx_out  = loss_out + 1;

    float* wsf = (float*)d_ws;
    float* acc        = wsf;                 // [0]
    int*   e2max_bits = (int*)(wsf + 1);     // [1]
    float* e2 = wsf + 16;                    // K floats
    float* x2 = wsf + 16 + K_CB;             // N floats   (ws total ~295 KB, as round 3)

    // scratch inside the zq output region (16.8 MB); gather overwrites it at the end
    int* zqi = (int*)zq_out;
    int* cand = zqi;                                        // N*CAP ints (6.3 MB)
    int* cnt  = zqi + (size_t)N_PTS * CAP;                  // N ints
    unsigned short* z16 = (unsigned short*)(zqi + (size_t)N_PTS * (CAP + 1)); // N*64 bf16
    unsigned short* c16 = z16 + (size_t)N_PTS * D_DIM;      // K*64 bf16 (total 15.2 MB < 16.8)

    hipMemsetAsync(d_ws, 0, 64, stream);   // zero acc + e2max (capture-safe memset node)
    vq_prep_cb<<<K_CB  / 64, 256, 0, stream>>>(cb, e2, c16, e2max_bits);
    vq_prep_z <<<N_PTS / 64, 256, 0, stream>>>(z, x2, z16);
    vq_coarse <<<N_PTS / 128, 256, 0, stream>>>(z16, c16, e2, x2, e2max_bits, cand, cnt);
    vq_rescore<<<N_PTS / 256, 256, 0, stream>>>(z, cb, e2, x2, cand, cnt, idx_out);
    vq_gather <<<N_PTS / 4, 256, 0, stream>>>(z, cb, idx_out, zq_out, acc);
    vq_final  <<<1, 1, 0, stream>>>(acc, loss_out);
}

// Round 5
// 391.516 us; speedup vs baseline: 40.6095x; 1.5715x over previous
//
#include <hip/hip_runtime.h>
#include <hip/hip_bf16.h>

#define N_PTS 65536
#define K_CB  8192
#define D_DIM 64
#define CAPS  63   // candidate slots per row; slot 63 holds the count

typedef float f32x4 __attribute__((ext_vector_type(4)));
typedef short s16x8 __attribute__((ext_vector_type(8)));

__device__ __forceinline__ unsigned bfpack2(float a, float b) {
    union { __hip_bfloat162 h2; unsigned u; } cv;
    cv.h2 = __float22bfloat162_rn(make_float2(a, b));   // RNE pair cvt (v_cvt_pk_bf16_f32)
    return cv.u;
}

// ---- node 1: e2[K], x2[N] (numpy-pairwise exact) + per-block e2 maxes ----
__global__ __launch_bounds__(256) void vq_prep(
        const float* __restrict__ z, const float* __restrict__ cb,
        float* __restrict__ e2, float* __restrict__ x2, float* __restrict__ bmax) {
#pragma clang fp contract(off)
    __shared__ float sm[4];
    int b = blockIdx.x;
    int lane = threadIdx.x & 63;
    int wv = threadIdx.x >> 6;
    const float* src; float* dst; int row0;
    if (b < 128) { src = cb; dst = e2; row0 = b * 64 + wv * 16; }
    else         { src = z;  dst = x2; row0 = (b - 128) * 64 + wv * 16; }
    float lmax = 0.f;
    for (int r = 0; r < 16; ++r) {
        int row = row0 + r;
        float v = src[(size_t)row * D_DIM + lane];
        float w = v * v;
        float ra = w;
#pragma unroll
        for (int i = 1; i < 8; ++i) ra = ra + __shfl(w, lane + 8 * i, 64);
        float r0 = __shfl(ra, 0, 64), r1 = __shfl(ra, 1, 64),
              r2 = __shfl(ra, 2, 64), r3 = __shfl(ra, 3, 64),
              r4 = __shfl(ra, 4, 64), r5 = __shfl(ra, 5, 64),
              r6 = __shfl(ra, 6, 64), r7 = __shfl(ra, 7, 64);
        if (lane == 0) {
            float s = ((r0 + r1) + (r2 + r3)) + ((r4 + r5) + (r6 + r7));
            dst[row] = s;
            lmax = fmaxf(lmax, s);
        }
    }
    if (b < 128) {                 // block-uniform branch: syncthreads is safe
        if (lane == 0) sm[wv] = lmax;
        __syncthreads();
        if (threadIdx.x == 0)
            bmax[b] = fmaxf(fmaxf(sm[0], sm[1]), fmaxf(sm[2], sm[3]));
    }
}

// ---- node 2: single-sweep coarse argmin with online candidate collection ----
// bias -e2/2 in MFMA C-init => t = -2*acc; min-t == max-acc.
// Collect acc >= prefixMax - W/2 (superset guarantee); chunk 0 revisited at end.
__global__ __launch_bounds__(256, 3) void vq_coarse(
        const float* __restrict__ z, const float* __restrict__ cb,
        const float* __restrict__ e2, const float* __restrict__ x2,
        const float* __restrict__ bmax, int* __restrict__ cand) {
    __shared__ __align__(16) unsigned short zb[128 * 64];    // 16 KB
    __shared__ __align__(16) unsigned short cbb[256 * 64];   // 32 KB
    __shared__ float e2h[256];
    __shared__ int cntS[128];
    const int tid = threadIdx.x;
    const int w = tid >> 6, l = tid & 63, tx = l & 15, q = l >> 4;
    const int n0 = blockIdx.x * 128;

    if (tid < 128) cntS[tid] = 0;

    // stage z tile fp32->bf16, swizzled (proven conflict-free: R4 conflicts=218)
#pragma unroll
    for (int i = 0; i < 4; ++i) {
        int lin = tid + 256 * i;
        int row = lin >> 3, u = lin & 7;
        const float4* p = (const float4*)(z + (size_t)(n0 + row) * D_DIM + u * 8);
        float4 a = p[0], b2 = p[1];
        uint4 pk;
        pk.x = bfpack2(a.x, a.y);   pk.y = bfpack2(a.z, a.w);
        pk.z = bfpack2(b2.x, b2.y); pk.w = bfpack2(b2.z, b2.w);
        *(uint4*)&zb[row * 64 + ((u ^ (row & 7)) * 8)] = pk;
    }

    float e2m;   // global e2max from prep's per-block maxes
    {
        float v = fmaxf(bmax[l], bmax[l + 64]);
#pragma unroll
        for (int m = 1; m < 64; m <<= 1) v = fmaxf(v, __shfl_xor(v, m, 64));
        e2m = v;
    }

    float halfW[8], A[8], M[8];
#pragma unroll
    for (int i = 0; i < 8; ++i) {
        int row = n0 + w * 32 + (i >> 2) * 16 + q * 4 + (i & 3);
        halfW[i] = 0.0175f * sqrtf(x2[row] * e2m) + 1e-4f;   // W/2, R4-proven constant
        A[i] = 3.0e38f;      // no collection during first chunk
        M[i] = -3.4e38f;
    }

    s16x8 afr[2][2];

    for (int it = 0; it < 33; ++it) {        // 32 chunks + chunk-0 revisit
        const int kc = (it < 32) ? it : 0;
        __syncthreads();
        {
            const size_t base = (size_t)kc * 256 * D_DIM;
#pragma unroll
            for (int i = 0; i < 8; ++i) {
                int lin = tid + 256 * i;
                int row = lin >> 3, u = lin & 7;
                const float4* p = (const float4*)(cb + base + (size_t)row * D_DIM + u * 8);
                float4 a = p[0], b2 = p[1];
                uint4 pk;
                pk.x = bfpack2(a.x, a.y);   pk.y = bfpack2(a.z, a.w);
                pk.z = bfpack2(b2.x, b2.y); pk.w = bfpack2(b2.z, b2.w);
                *(uint4*)&cbb[row * 64 + ((u ^ (row & 7)) * 8)] = pk;
            }
            e2h[tid] = e2[kc * 256 + tid];
        }
        __syncthreads();

        if (it == 0) {    // A-frags register-resident for the whole kernel
#pragma unroll
            for (int rt = 0; rt < 2; ++rt)
#pragma unroll
                for (int ks = 0; ks < 2; ++ks) {
                    int row = w * 32 + rt * 16 + tx;
                    afr[rt][ks] = *(const s16x8*)&zb[row * 64 + (((ks * 4 + q) ^ (tx & 7)) * 8)];
                }
        }

        const bool collect = (it > 0);
        for (int ct = 0; ct < 16; ++ct) {
            int crow = ct * 16 + tx;
            float bias = -0.5f * e2h[crow];
            s16x8 b0 = *(const s16x8*)&cbb[crow * 64 + ((q ^ (tx & 7)) * 8)];
            s16x8 b1 = *(const s16x8*)&cbb[crow * 64 + (((4 + q) ^ (tx & 7)) * 8)];
            int kglob = kc * 256 + crow;
#pragma unroll
            for (int rt = 0; rt < 2; ++rt) {
                f32x4 acc = {bias, bias, bias, bias};
                acc = __builtin_amdgcn_mfma_f32_16x16x32_bf16(afr[rt][0], b0, acc, 0, 0, 0);
                acc = __builtin_amdgcn_mfma_f32_16x16x32_bf16(afr[rt][1], b1, acc, 0, 0, 0);
#pragma unroll
                for (int r = 0; r < 4; ++r) {
                    int i = rt * 4 + r;
                    M[i] = fmaxf(M[i], acc[r]);
                    if (collect && acc[r] >= A[i]) {   // rare branch
                        int row = w * 32 + rt * 16 + q * 4 + r;
                        int slot = atomicAdd(&cntS[row], 1);
                        if (slot < CAPS)
                            cand[(size_t)(n0 + row) * 64 + slot] = kglob;
                    }
                }
            }
        }
        if (it < 32) {   // cross-lane (tx) prefix max -> new threshold
#pragma unroll
            for (int i = 0; i < 8; ++i) {
                float v = M[i];
                v = fmaxf(v, __shfl_xor(v, 1, 64));
                v = fmaxf(v, __shfl_xor(v, 2, 64));
                v = fmaxf(v, __shfl_xor(v, 4, 64));
                v = fmaxf(v, __shfl_xor(v, 8, 64));
                M[i] = v;
                A[i] = v - halfW[i];
            }
        }
    }
    __syncthreads();
    if (tid < 128) cand[(size_t)(n0 + tid) * 64 + 63] = cntS[tid];
}

// ---- exact fp32 rescore: bit-identical to the round-3/4 passing pipeline ----
__device__ __forceinline__ float exact_score(const float* zr, const float* __restrict__ cb,
                                             const float* __restrict__ e2, float x2v, int k) {
    const float4* c4 = (const float4*)(cb + (size_t)k * D_DIM);
    float g = 0.f;
#pragma unroll
    for (int j = 0; j < 16; ++j) {
        float4 v = c4[j];
        g = fmaf(zr[4 * j + 0], v.x, g);
        g = fmaf(zr[4 * j + 1], v.y, g);
        g = fmaf(zr[4 * j + 2], v.z, g);
        g = fmaf(zr[4 * j + 3], v.w, g);
    }
    return fmaf(-2.f, g, x2v) + e2[k];
}

// ---- node 3: rescore + gather + straight-through write + loss partials ----
__global__ __launch_bounds__(256, 2) void vq_rescore(
        const float* __restrict__ z, const float* __restrict__ cb,
        const float* __restrict__ e2, const float* __restrict__ x2,
        int* __restrict__ slots, float* __restrict__ idx_out,
        float* __restrict__ partials) {
    int tid = threadIdx.x;
    int n = blockIdx.x * 256 + tid;
    float zr[64];
    const float4* z4 = (const float4*)(z + (size_t)n * D_DIM);
#pragma unroll
    for (int i = 0; i < 16; ++i) {
        float4 v = z4[i];
        zr[4 * i] = v.x; zr[4 * i + 1] = v.y; zr[4 * i + 2] = v.z; zr[4 * i + 3] = v.w;
    }
    float x2v = x2[n];
    int cnt = slots[(size_t)n * 64 + 63];
    float bs = 3.4e38f; int bk = 0x7fffffff;
    if (cnt <= CAPS) {
        for (int i = 0; i < cnt; ++i) {
            int k = slots[(size_t)n * 64 + i];
            float s = exact_score(zr, cb, e2, x2v, k);
            if (s < bs || (s == bs && k < bk)) { bs = s; bk = k; }
        }
    }
    // wave-cooperative full scan for overflowed rows (cheap, ~never taken)
    unsigned long long mask = __ballot(cnt > CAPS);
    while (mask) {
        int src = __ffsll((long long)mask) - 1;
        mask &= (mask - 1);
        int rown = __shfl(n, src, 64);
        float x2s = __shfl(x2v, src, 64);
        float zs[64];
        const float4* zz = (const float4*)(z + (size_t)rown * D_DIM);
#pragma unroll
        for (int i = 0; i < 16; ++i) {
            float4 v = zz[i];
            zs[4 * i] = v.x; zs[4 * i + 1] = v.y; zs[4 * i + 2] = v.z; zs[4 * i + 3] = v.w;
        }
        float fb = 3.4e38f; int fk = 0x7fffffff;
        for (int k = (tid & 63); k < K_CB; k += 64) {
            float s = exact_score(zs, cb, e2, x2s, k);
            if (s < fb || (s == fb && k < fk)) { fb = s; fk = k; }
        }
#pragma unroll
        for (int m = 1; m < 64; m <<= 1) {
            float ov = __shfl_xor(fb, m, 64);
            int   ok = __shfl_xor(fk, m, 64);
            if (ov < fb || (ov == fb && ok < fk)) { fb = ov; fk = ok; }
        }
        if ((tid & 63) == src) { bs = fb; bk = fk; }
    }
    idx_out[n] = (float)bk;
    __threadfence_block();   // all slot reads drained before aliased zq writes

    float lsum = 0.f;
    const float4* c4 = (const float4*)(cb + (size_t)bk * D_DIM);
    float4* o4 = (float4*)((float*)slots + (size_t)n * 64);   // own slot, float view
#pragma unroll
    for (int j = 0; j < 16; ++j) {
        float4 c = c4[j];
        float4 o;
        float d0 = c.x - zr[4 * j];     o.x = zr[4 * j]     + d0;
        float d1 = c.y - zr[4 * j + 1]; o.y = zr[4 * j + 1] + d1;
        float d2 = c.z - zr[4 * j + 2]; o.z = zr[4 * j + 2] + d2;
        float d3 = c.w - zr[4 * j + 3]; o.w = zr[4 * j + 3] + d3;
        lsum += d0 * d0 + d1 * d1 + d2 * d2 + d3 * d3;
        o4[j] = o;
    }
    __shared__ float red[256];
    red[tid] = lsum;
    __syncthreads();
    for (int s = 128; s > 0; s >>= 1) {
        if (tid < s) red[tid] += red[tid + s];
        __syncthreads();
    }
    if (tid == 0) partials[blockIdx.x] = red[0];
}

// ---- node 4: final loss ----
__global__ void vq_final(const float* __restrict__ partials, float* __restrict__ loss_out) {
    __shared__ float red[256];
    int tid = threadIdx.x;
    red[tid] = partials[tid];
    __syncthreads();
    for (int s = 128; s > 0; s >>= 1) {
        if (tid < s) red[tid] += red[tid + s];
        __syncthreads();
    }
    if (tid == 0) *loss_out = 1.25f * red[0] / (float)(N_PTS * D_DIM);
}

extern "C" void kernel_launch(void* const* d_in, const int* in_sizes, int n_in,
                              void* d_out, int out_size, void* d_ws, size_t ws_size,
                              hipStream_t stream) {
    const float* z  = (const float*)d_in[0];
    const float* cb = (const float*)d_in[1];
    float* out      = (float*)d_out;
    float* zq_out   = out;                          // [N*64]; doubles as cand slots
    float* loss_out = out + (size_t)N_PTS * D_DIM;  // [1]
    float* idx_out  = loss_out + 1;                 // [N]; [0..127] doubles as bmax scratch

    float* wsf = (float*)d_ws;
    float* partials = wsf;                          // 256 floats (always fully written)
    float* e2 = wsf + 256;                          // K floats
    float* x2 = wsf + 256 + K_CB;                   // N floats (~296 KB total)

    int* cand = (int*)zq_out;
    float* bmax = idx_out;                          // overwritten by rescore afterwards

    vq_prep   <<<128 + N_PTS / 64, 256, 0, stream>>>(z, cb, e2, x2, bmax);
    vq_coarse <<<N_PTS / 128, 256, 0, stream>>>(z, cb, e2, x2, bmax, cand);
    vq_rescore<<<N_PTS / 256, 256, 0, stream>>>(z, cb, e2, x2, cand, idx_out, partials);
    vq_final  <<<1, 256, 0, stream>>>(partials, loss_out);
}